// Round 10
// baseline (418.057 us; speedup 1.0000x reference)
//
#include <hip/hip_runtime.h>

#define BINS  30
#define NROWS 8192
#define NCOLS 2048
#define COLS_PER_BLK 256                 // grid.x = 8
#define ROWS_PER_BLK 128                 // grid.y = 64
#define YSLICES 64
#define CELLS   (BINS * NCOLS)           // 61440

#define FIXED_SCALE 16384.0f             // 2^14 fixed point for bce
#define CNT_SHIFT   24                   // count bits [24:31], sum in [0:24)
#define SUM_MASK    ((1u << CNT_SHIFT) - 1)

// ws layout (bytes) — unchanged:
//   part : u32[YSLICES][BINS][NCOLS]   (15.7 MB)
//   blockPart: float[8]   (unused as of R10, kept for layout stability)
//   ctr  : u32
#define WS_PART  0
#define WS_BPART (YSLICES * BINS * NCOLS * 4)
#define WS_CTR   (WS_BPART + 8 * 4)

// ---------------------------------------------------------------------------
// Kernel A (FROZEN since R3): direct column ownership.
// Empirical wall: 49-55 us across SIX structures (LDS-atomic R0/R1,
// staged-owner R2, direct-owner R3, narrow-block 36%-occ R8,
// producer/consumer gll+vmcnt R9); loads-only 18 us, math-only 16 us.
// The interaction term resists every mechanism tried; frozen.
// ---------------------------------------------------------------------------
__global__ __launch_bounds__(256, 5) void k_main(
    const float* __restrict__ preds, const int* __restrict__ targets,
    unsigned int* __restrict__ part, unsigned int* __restrict__ ctr)
{
    __shared__ unsigned int H[BINS * COLS_PER_BLK];   // 30720 B
    const int t = threadIdx.x;
    if (blockIdx.x == 0 && blockIdx.y == 0 && t == 0) atomicExch(ctr, 0u);
    #pragma unroll
    for (int i = 0; i < BINS; ++i) H[i * COLS_PER_BLK + t] = 0u;
    __syncthreads();

    const int col = blockIdx.x * COLS_PER_BLK + t;
    const int r0  = blockIdx.y * ROWS_PER_BLK;
    const float* P = preds   + (size_t)r0 * NCOLS + col;
    const int*   T = targets + (size_t)r0 * NCOLS + col;

    float pc[8]; int tc[8];
    #pragma unroll
    for (int r = 0; r < 8; ++r) { pc[r] = P[r * NCOLS]; tc[r] = T[r * NCOLS]; }

    #pragma unroll 1
    for (int batch = 0; batch < ROWS_PER_BLK / 8; ++batch) {
        float pn[8]; int tn[8];
        if (batch < ROWS_PER_BLK / 8 - 1) {
            P += 8 * NCOLS; T += 8 * NCOLS;
            #pragma unroll
            for (int r = 0; r < 8; ++r) { pn[r] = P[r * NCOLS]; tn[r] = T[r * NCOLS]; }
        }
        __builtin_amdgcn_sched_barrier(0);

        #pragma unroll
        for (int r = 0; r < 8; ++r) {
            float p  = pc[r];
            float pp = tc[r] ? -p : p;
            float e  = __expf(-fabsf(pp));
            float d  = 1.0f + e;
            float r1 = __builtin_amdgcn_rcpf(d);
            float g  = (pp >= 0.0f) ? r1 : e * r1;
            int   b  = (int)(g * 30.0f);
            b = b > (BINS - 1) ? (BINS - 1) : b;
            float bce = fmaxf(pp, 0.0f) + __logf(d);
            unsigned int pk = (1u << CNT_SHIFT)
                | (unsigned int)(bce * FIXED_SCALE + 0.5f);
            H[b * COLS_PER_BLK + t] += pk;
        }
        #pragma unroll
        for (int r = 0; r < 8; ++r) { pc[r] = pn[r]; tc[r] = tn[r]; }
    }
    __syncthreads();

    const size_t outBase = (size_t)blockIdx.y * BINS * NCOLS
                         + (size_t)blockIdx.x * COLS_PER_BLK;
    for (int i = t; i < BINS * COLS_PER_BLK; i += 256)
        part[outBase + (size_t)(i >> 8) * NCOLS + (i & 255)] = H[i];
}

// ---------------------------------------------------------------------------
// Kernel B (R10): y-slice reduction (R5's verified in-place scheme) FUSED
// with the per-column contraction + finale via last-block-done.
// Phase 1 (960 blocks x 256): thread (chunk, cell) sums 16 slices of its
// cell in-place (cnt -> slice 16*chunk, sum -> slice 16*chunk+1) — byte-
// identical to R5's k_reduce16.
// Phase 2: threadfence -> syncthreads -> t0 atomicAdd(ctr); the block that
// sees 959 replays the OLD k_tail EXACTLY, 8 column-groups sequentially:
// same thread<->column map per group g (wave w lane l -> col g*256+w*64+l),
// same ordered b-loop, same 64-wide shfl tree, same wave_sums[4], same
// ordered g=0..7 double accumulation -> bit-identical out[0].
// Cross-XCD visibility: writers fence before the release-add; the finale's
// XCD never cached other blocks' partial addresses (disjoint per-block
// read/write sets), so its plain loads miss local L2 and hit the device
// coherence point where the fenced writebacks landed.
// ---------------------------------------------------------------------------
__global__ __launch_bounds__(256) void k_reduce2(
    unsigned int* __restrict__ part, const float* __restrict__ acc_sum,
    unsigned int* __restrict__ ctr, float* __restrict__ out)
{
    __shared__ float wave_sums[4];
    __shared__ unsigned int amLast;
    const int t = threadIdx.x;

    // ---- phase 1: identical to R5 k_reduce16 ----
    const int gid   = blockIdx.x * 256 + t;             // 0 .. 245759
    const int chunk = gid / CELLS;                      // 0..3
    const int cell  = gid % CELLS;
    unsigned int* Pp = part + (size_t)(chunk * 16) * CELLS + cell;

    unsigned int c = 0u, s = 0u;
    #pragma unroll
    for (int y = 0; y < 16; ++y) {
        const unsigned int v = Pp[(size_t)y * CELLS];
        c += v >> CNT_SHIFT;
        s += v & SUM_MASK;
    }
    Pp[0]     = c;      // slice 16*chunk   : cnt partial
    Pp[CELLS] = s;      // slice 16*chunk+1 : sum partial

    // ---- last-block-done handoff ----
    __threadfence();                       // release this block's writes
    __syncthreads();                       // all threads' stores fenced
    if (t == 0) amLast = (atomicAdd(ctr, 1u) == 959u) ? 1u : 0u;
    __syncthreads();

    if (amLast) {
        __threadfence();                   // acquire all blocks' partials
        double dsum = 0.0;
        #pragma unroll 1
        for (int g = 0; g < 8; ++g) {      // replicate old k_tail block g
            const int cg = g * 256 + t;
            float colsum = 0.0f;
            int n = 0;
            #pragma unroll
            for (int b = 0; b < BINS; ++b) {
                const int cl = b * NCOLS + cg;
                unsigned int cu = part[(size_t) 0 * CELLS + cl]
                                + part[(size_t)16 * CELLS + cl]
                                + part[(size_t)32 * CELLS + cl]
                                + part[(size_t)48 * CELLS + cl];
                unsigned int su = part[(size_t) 1 * CELLS + cl]
                                + part[(size_t)17 * CELLS + cl]
                                + part[(size_t)33 * CELLS + cl]
                                + part[(size_t)49 * CELLS + cl];
                const float cnt = (float)cu;
                if (cnt >= 1.0f) {
                    n += 1;
                    float acc_new = 0.75f * acc_sum[cl] + 0.25f * cnt;
                    colsum += ((float)su * (1.0f / FIXED_SCALE)) / acc_new;
                }
            }
            colsum /= (float)((n > 1 ? n : 1) * NCOLS);

            #pragma unroll
            for (int off = 32; off > 0; off >>= 1)
                colsum += __shfl_down(colsum, off, 64);
            if ((t & 63) == 0) wave_sums[t >> 6] = colsum;
            __syncthreads();
            if (t == 0) {
                const float sblk = wave_sums[0] + wave_sums[1]
                                 + wave_sums[2] + wave_sums[3];
                dsum += (double)sblk;      // same order as old k_final
            }
            __syncthreads();
        }
        if (t == 0) out[0] = (float)dsum;
    }
}

extern "C" void kernel_launch(void* const* d_in, const int* in_sizes, int n_in,
                              void* d_out, int out_size, void* d_ws, size_t ws_size,
                              hipStream_t stream)
{
    const float* preds   = (const float*)d_in[0];
    const int*   targets = (const int*)d_in[1];
    const float* acc_sum = (const float*)d_in[2];

    unsigned int* part = (unsigned int*)((char*)d_ws + WS_PART);
    unsigned int* ctr  = (unsigned int*)((char*)d_ws + WS_CTR);

    dim3 gA(NCOLS / COLS_PER_BLK, NROWS / ROWS_PER_BLK);   // (8, 64) = 512 blocks
    k_main<<<gA, 256, 0, stream>>>(preds, targets, part, ctr);

    k_reduce2<<<(4 * CELLS) / 256, 256, 0, stream>>>(part, acc_sum, ctr,
                                                     (float*)d_out);
}

// Round 11
// 346.761 us; speedup vs baseline: 1.2056x; 1.2056x over previous
//
#include <hip/hip_runtime.h>

#define BINS  30
#define NROWS 8192
#define NCOLS 2048
#define COLS_PER_BLK 256                 // grid.x = 8
#define ROWS_PER_BLK 128                 // grid.y = 64
#define YSLICES 64
#define CELLS   (BINS * NCOLS)           // 61440

#define FIXED_SCALE 16384.0f             // 2^14 fixed point for bce
#define CNT_SHIFT   24                   // count bits [24:31], sum in [0:24)
#define SUM_MASK    ((1u << CNT_SHIFT) - 1)

// ws layout (bytes) — same footprint as R0 (proven to fit):
//   part   : u32[YSLICES][BINS][NCOLS]  (15.7 MB)
//   accCnt : u32[CELLS]                 (245760 B)
//   accSum : u32[CELLS]                 (245760 B)
//   ctr    : u32
#define WS_PART  0
#define WS_ACNT  (YSLICES * BINS * NCOLS * 4)
#define WS_ASUM  (WS_ACNT + CELLS * 4)
#define WS_CTR   (WS_ASUM + CELLS * 4)

// ---------------------------------------------------------------------------
// Kernel A (frozen since R3, + 1-store acc zeroing prologue): direct column
// ownership. 49-55us wall across six structures; loads-only 18us, math-only
// 16us — interaction term unexplained, frozen at empirical wall.
// acc zeroing: block bid zeroes acc[240*bid .. +240) (2*CELLS u32 total,
// 512 blocks x 240). Plain stores; the runtime's end-of-kernel release
// (L2 writeback) lands them at the coherence point before k_fused's
// memory-side atomics accumulate onto them.
// ---------------------------------------------------------------------------
__global__ __launch_bounds__(256, 5) void k_main(
    const float* __restrict__ preds, const int* __restrict__ targets,
    unsigned int* __restrict__ part, unsigned int* __restrict__ acc,
    unsigned int* __restrict__ ctr)
{
    __shared__ unsigned int H[BINS * COLS_PER_BLK];   // 30720 B
    const int t = threadIdx.x;
    const int bid = blockIdx.y * 8 + blockIdx.x;      // 0..511
    if (bid == 0 && t == 0) atomicExch(ctr, 0u);
    if (t < 240) acc[240 * bid + t] = 0u;             // zero accCnt+accSum
    #pragma unroll
    for (int i = 0; i < BINS; ++i) H[i * COLS_PER_BLK + t] = 0u;
    __syncthreads();

    const int col = blockIdx.x * COLS_PER_BLK + t;
    const int r0  = blockIdx.y * ROWS_PER_BLK;
    const float* P = preds   + (size_t)r0 * NCOLS + col;
    const int*   T = targets + (size_t)r0 * NCOLS + col;

    float pc[8]; int tc[8];
    #pragma unroll
    for (int r = 0; r < 8; ++r) { pc[r] = P[r * NCOLS]; tc[r] = T[r * NCOLS]; }

    #pragma unroll 1
    for (int batch = 0; batch < ROWS_PER_BLK / 8; ++batch) {
        float pn[8]; int tn[8];
        if (batch < ROWS_PER_BLK / 8 - 1) {
            P += 8 * NCOLS; T += 8 * NCOLS;
            #pragma unroll
            for (int r = 0; r < 8; ++r) { pn[r] = P[r * NCOLS]; tn[r] = T[r * NCOLS]; }
        }
        __builtin_amdgcn_sched_barrier(0);

        #pragma unroll
        for (int r = 0; r < 8; ++r) {
            float p  = pc[r];
            float pp = tc[r] ? -p : p;
            float e  = __expf(-fabsf(pp));
            float d  = 1.0f + e;
            float r1 = __builtin_amdgcn_rcpf(d);
            float g  = (pp >= 0.0f) ? r1 : e * r1;
            int   b  = (int)(g * 30.0f);
            b = b > (BINS - 1) ? (BINS - 1) : b;
            float bce = fmaxf(pp, 0.0f) + __logf(d);
            unsigned int pk = (1u << CNT_SHIFT)
                | (unsigned int)(bce * FIXED_SCALE + 0.5f);
            H[b * COLS_PER_BLK + t] += pk;
        }
        #pragma unroll
        for (int r = 0; r < 8; ++r) { pc[r] = pn[r]; tc[r] = tn[r]; }
    }
    __syncthreads();

    const size_t outBase = (size_t)blockIdx.y * BINS * NCOLS
                         + (size_t)blockIdx.x * COLS_PER_BLK;
    for (int i = t; i < BINS * COLS_PER_BLK; i += 256)
        part[outBase + (size_t)(i >> 8) * NCOLS + (i & 255)] = H[i];
}

// ---------------------------------------------------------------------------
// Kernel B (R11): fused reduce + contraction + finale, FENCE-FREE writers.
// R10 post-mortem: 960 per-block __threadfence() = per-block L2 writeback
// storm = 277us. Fix: publish partials via device-scope atomicAdd (executes
// at the memory-side coherence point — no L2 writeback involved), then
// __syncthreads (drains each wave's vmcnt -> all the block's atomics
// complete) -> t0 atomicAdd(ctr). Integer adds in any order = exact, so
// accCnt/accSum totals are bit-identical to the old 4-partial chain.
// The 960th block replays R10's verified finale chain (same thread<->col
// map per group g, same ordered b-loop, same shfl tree, same wave_sums[4],
// same ordered g=0..7 double accumulation -> bit-identical out[0]), reading
// accCnt/accSum via atomic fetches (atomicAdd(p,0): coherent at the memory
// side, immune to stale clean L2 lines left by k_main's zeroing stores) +
// one acquire fence in this single block (cheap: ONE writeback/inv, not 960).
// ema (the acc_sum EMA input) is read-only -> plain loads safe.
// ---------------------------------------------------------------------------
__global__ __launch_bounds__(256) void k_fused(
    const unsigned int* __restrict__ part,
    unsigned int* __restrict__ accCnt, unsigned int* __restrict__ accSum,
    const float* __restrict__ ema,
    unsigned int* __restrict__ ctr, float* __restrict__ out)
{
    __shared__ float wave_sums[4];
    __shared__ unsigned int amLast;
    const int t = threadIdx.x;

    // ---- phase 1: 16-slice partial sums (R5's verified decomposition) ----
    const int gid   = blockIdx.x * 256 + t;             // 0 .. 245759
    const int chunk = gid / CELLS;                      // 0..3
    const int cell  = gid % CELLS;
    const unsigned int* Pp = part + (size_t)(chunk * 16) * CELLS + cell;

    unsigned int c = 0u, s = 0u;
    #pragma unroll
    for (int y = 0; y < 16; ++y) {
        const unsigned int v = Pp[(size_t)y * CELLS];
        c += v >> CNT_SHIFT;
        s += v & SUM_MASK;
    }
    atomicAdd(&accCnt[cell], c);          // memory-side, no fence needed
    atomicAdd(&accSum[cell], s);

    // ---- last-block-done handoff (fence-free for the 959) ----
    __syncthreads();                      // per-wave vmcnt drain: atomics done
    if (t == 0) amLast = (atomicAdd(ctr, 1u) == 959u) ? 1u : 0u;
    __syncthreads();
    if (!amLast) return;

    // ---- finale (single block): R10's verified bit-exact chain ----
    __threadfence();                      // one acquire fence, one block
    double dsum = 0.0;
    #pragma unroll 1
    for (int g = 0; g < 8; ++g) {         // replicate old k_tail block g
        const int cg = g * 256 + t;
        float colsum = 0.0f;
        int n = 0;
        #pragma unroll
        for (int b = 0; b < BINS; ++b) {
            const int cl = b * NCOLS + cg;
            const unsigned int cu = atomicAdd(&accCnt[cl], 0u);  // coherent fetch
            const unsigned int su = atomicAdd(&accSum[cl], 0u);
            const float cnt = (float)cu;
            if (cnt >= 1.0f) {
                n += 1;
                float acc_new = 0.75f * ema[cl] + 0.25f * cnt;
                colsum += ((float)su * (1.0f / FIXED_SCALE)) / acc_new;
            }
        }
        colsum /= (float)((n > 1 ? n : 1) * NCOLS);

        #pragma unroll
        for (int off = 32; off > 0; off >>= 1)
            colsum += __shfl_down(colsum, off, 64);
        if ((t & 63) == 0) wave_sums[t >> 6] = colsum;
        __syncthreads();
        if (t == 0) {
            const float sblk = wave_sums[0] + wave_sums[1]
                             + wave_sums[2] + wave_sums[3];
            dsum += (double)sblk;         // same order as old k_final
        }
        __syncthreads();
    }
    if (t == 0) out[0] = (float)dsum;
}

extern "C" void kernel_launch(void* const* d_in, const int* in_sizes, int n_in,
                              void* d_out, int out_size, void* d_ws, size_t ws_size,
                              hipStream_t stream)
{
    const float* preds   = (const float*)d_in[0];
    const int*   targets = (const int*)d_in[1];
    const float* acc_sum = (const float*)d_in[2];

    unsigned int* part   = (unsigned int*)((char*)d_ws + WS_PART);
    unsigned int* accCnt = (unsigned int*)((char*)d_ws + WS_ACNT);
    unsigned int* accSum = (unsigned int*)((char*)d_ws + WS_ASUM);
    unsigned int* ctr    = (unsigned int*)((char*)d_ws + WS_CTR);

    dim3 gA(NCOLS / COLS_PER_BLK, NROWS / ROWS_PER_BLK);   // (8, 64) = 512 blocks
    k_main<<<gA, 256, 0, stream>>>(preds, targets, part, accCnt, ctr);

    k_fused<<<(4 * CELLS) / 256, 256, 0, stream>>>(part, accCnt, accSum,
                                                   acc_sum, ctr, (float*)d_out);
}